// Round 5
// baseline (571.282 us; speedup 1.0000x reference)
//
#include <hip/hip_runtime.h>

#define NROW 6
#define NCOL 6
#define BATCH 1024

// One block = one sample. Exact 6x6 PEPS (D=4, open boundary) contracted by
// row-major single-site absorption. The inter-step intermediate (up to 4^7
// elements) lives in REGISTERS: thread t holds, for each (g', z, s), the
// element whose spectator index m = t + 256*s. Each step streams the previous
// state through LDS one g-slice at a time (<= 4096 floats), double-buffered
// with globally alternating parity. Peak LDS = 32 KB.
// The 16x16 site matrix M[(g',z)][(g,x)] = T[u=x][r=g'][d=z][l=g] is held in
// wave registers (lane (g'*4+z)*4+g holds the 4 x-values) and broadcast with
// constant-lane __shfl (v_readlane).
// __launch_bounds__(256,2) is REQUIRED: without it the allocator caps at 64
// VGPRs (default flat-work-group-size 1024) and spills ~70 floats/thread to
// scratch (R3: VGPR=64, WRITE_SIZE=7.2MB of spill stores, VALUBusy 44%).
__global__ __launch_bounds__(256, 2)
void peps_amp_kernel(const int* __restrict__ X,
                     const float* __restrict__ Tg,
                     float* __restrict__ out)
{
    __shared__ float buf[2][4096];        // 32 KB total

    const int b    = blockIdx.x;
    const int t    = threadIdx.x;
    const int lane = t & 63;
    const int mrow = lane >> 2;           // g' = mrow>>2, z = mrow&3
    const int mq   = lane & 3;            // g
    // T site axes (u,r,d,l) strides (64,16,4,1)
    const int moff = (mrow >> 2) * 16 + (mrow & 3) * 4 + mq;
    const int* xrow = X + b * (NROW * NCOL);

    // M for step 0
    float m4[4];
    {
        const int spin = xrow[0];
        const float* Ts = Tg + (size_t)spin * 256;
        #pragma unroll
        for (int x = 0; x < 4; ++x) m4[x] = Ts[x * 64 + moff];
    }

    float r[4][4][4];                     // state [g'][z][s]
    int pm_count = 1;                     // prev step's spectator count
    int pz4 = 0;                          // prev step's zs==4 ?
    int pb = 0;                           // LDS slice parity (uniform)
    int step = 0;

    for (int row = 0; row < NROW; ++row) {
        const int xs = (row == 0) ? 1 : 4;          // up bond (top edge -> 1)
        const int zs = (row == NROW - 1) ? 1 : 4;   // down bond (bottom edge -> 1)
        for (int c = 0; c < NCOL; ++c, ++step) {
            const int gin   = (c == 0) ? 1 : 4;     // left bond (left edge -> 1)
            const int gout  = (c == NCOL - 1) ? 1 : 4;  // right bond (right edge -> 1)
            const int mbits = ((xs == 4) ? 2 * (5 - c) : 0) + ((zs == 4) ? 2 * c : 0);
            const int mcount = 1 << mbits;          // spectators this step

            // prefetch next step's M (L2-resident; hidden under compute)
            float m4n[4] = {0.f, 0.f, 0.f, 0.f};
            if (step + 1 < NROW * NCOL) {
                const int spin = xrow[step + 1];
                const float* Ts = Tg + (size_t)((step + 1) * 2 + spin) * 256;
                #pragma unroll
                for (int x = 0; x < 4; ++x) m4n[x] = Ts[x * 64 + moff];
            }

            float acc[4][4][4] = {};                // next state [gp][z][s]

            #pragma unroll
            for (int g = 0; g < 4; ++g) {
                if (g < gin) {                      // uniform guard
                    float* sb = buf[pb]; pb ^= 1;
                    // ---- stage slice g of the previous state ----
                    if (step == 0) {
                        if (t == 0) sb[0] = 1.0f;   // scalar seed
                    } else {
                        #pragma unroll
                        for (int s = 0; s < 4; ++s) {
                            const int mp = t + 256 * s;
                            if (mp < pm_count) {
                                if (pz4) {
                                    *(float4*)&sb[mp << 2] = make_float4(
                                        r[g][0][s], r[g][1][s], r[g][2][s], r[g][3][s]);
                                } else {
                                    sb[mp] = r[g][0][s];
                                }
                            }
                        }
                    }
                    __syncthreads();
                    // ---- read slice + accumulate ----
                    #pragma unroll
                    for (int x = 0; x < 4; ++x) {
                        if (x < xs) {               // uniform guard
                            float wv[4];
                            #pragma unroll
                            for (int s = 0; s < 4; ++s) {
                                const int m = t + 256 * s;
                                wv[s] = (m < mcount) ? sb[(x << mbits) + m] : 0.f;
                            }
                            #pragma unroll
                            for (int gp = 0; gp < 4; ++gp) {
                                if (gp < gout) {    // uniform guard (skip c==5 waste)
                                    #pragma unroll
                                    for (int z = 0; z < 4; ++z) {
                                        if (z < zs) {   // uniform guard (skip row-5 waste)
                                            const float mv =
                                                __shfl(m4[x], (((gp << 2) | z) << 2) | g, 64);
                                            #pragma unroll
                                            for (int s = 0; s < 4; ++s)
                                                acc[gp][z][s] += mv * wv[s];
                                        }
                                    }
                                }
                            }
                        }
                    }
                }
            }

            // ---- commit (zeros in masked gp/z slots are never staged later) ----
            #pragma unroll
            for (int gp = 0; gp < 4; ++gp)
                #pragma unroll
                for (int z = 0; z < 4; ++z)
                    #pragma unroll
                    for (int s = 0; s < 4; ++s) r[gp][z][s] = acc[gp][z][s];
            #pragma unroll
            for (int x = 0; x < 4; ++x) m4[x] = m4n[x];
            pm_count = mcount;
            pz4 = (zs == 4) ? 1 : 0;
        }
    }
    // after (5,5): only g'=0, z=0, m=0 valid -> thread 0, s=0
    if (t == 0) out[b] = r[0][0][0];
}

extern "C" void kernel_launch(void* const* d_in, const int* in_sizes, int n_in,
                              void* d_out, int out_size, void* d_ws, size_t ws_size,
                              hipStream_t stream) {
    const int*   X  = (const int*)d_in[0];     // x: [1024, 36] int32
    const float* Tg = (const float*)d_in[1];   // T: [6,6,2,4,4,4,4] fp32
    float* out = (float*)d_out;                // reference output dtype: float32
    (void)in_sizes; (void)n_in; (void)d_ws; (void)ws_size; (void)out_size;
    peps_amp_kernel<<<dim3(BATCH), dim3(256), 0, stream>>>(X, Tg, out);
}

// Round 6
// 546.984 us; speedup vs baseline: 1.0444x; 1.0444x over previous
//
#include <hip/hip_runtime.h>

#define NROW 6
#define NCOL 6
#define BATCH 1024
#define NSITE 36

// LDS address swizzle: XOR dword-addr bits [4:2] with bits [7:5]. The m=4t+s
// ownership makes b128 staging writes lane-stride 64B (8-way bank conflict
// without this); the swizzle spreads them over all 32 banks. Bits [1:0] are
// untouched so float4 contiguity and 16B alignment survive.
__device__ __forceinline__ int SWZ(int a) { return a ^ (((a >> 5) & 7) << 2); }

// Pre-transpose T[site][spin][u=x][r=gp][d=z][l=g] into
// Tm[((site*2+spin)*4+g)*64 + (gp*4+z)*4 + x]  (73,728 B in d_ws) so the main
// kernel's M rows are contiguous float4s at block-uniform addresses (s_load).
__global__ void peps_reorder_kernel(const float* __restrict__ T,
                                    float* __restrict__ Tm)
{
    int idx = blockIdx.x * 256 + threadIdx.x;
    if (idx >= NSITE * 2 * 256) return;
    int x  = idx & 3;
    int o  = (idx >> 2) & 15;         // o = gp*4 + z
    int g  = (idx >> 6) & 3;
    int sp = (idx >> 8) & 1;
    int st = idx >> 9;
    int gp = o >> 2, z = o & 3;
    Tm[idx] = T[st * 512 + sp * 256 + x * 64 + gp * 16 + z * 4 + g];
}

// One block = one sample; exact 6x6 PEPS (D=4) by row-major site absorption.
// State between steps lives in registers: thread t owns spectator indices
// m = 4t+s (s=0..3) for all 16 (g',z). Each step streams the state through a
// 16KB LDS slice per left-bond value g (parity double-buffered, 1 barrier per
// slice). All LDS traffic is b128 (see SWZ). M comes straight from Tm at a
// uniform address (scalar loads) — no shfl/bpermute (R5's 22%-VALUBusy killer).
__global__ __launch_bounds__(256, 2)
void peps_amp_kernel(const int* __restrict__ X, const float* __restrict__ Tm,
                     float* __restrict__ out)
{
    __shared__ float buf[2][4096];    // 32 KB

    const int b = blockIdx.x;
    const int t = threadIdx.x;
    const int* xrow = X + b * NSITE;

    // PHYS=2: pack all 36 spins into one scalar 64-bit mask.
    unsigned long long sm = 0ull;
    const int4* xp = (const int4*)xrow;           // 36 ints = 9 aligned int4
    #pragma unroll
    for (int k = 0; k < 9; ++k) {
        int4 v = xp[k];
        sm |= ((unsigned long long)(v.x & 1)) << (4 * k + 0);
        sm |= ((unsigned long long)(v.y & 1)) << (4 * k + 1);
        sm |= ((unsigned long long)(v.z & 1)) << (4 * k + 2);
        sm |= ((unsigned long long)(v.w & 1)) << (4 * k + 3);
    }
    {   // force SGPR so the Tm addresses below are provably uniform
        unsigned lo = __builtin_amdgcn_readfirstlane((int)(sm & 0xffffffffull));
        unsigned hi = __builtin_amdgcn_readfirstlane((int)(sm >> 32));
        sm = ((unsigned long long)hi << 32) | lo;
    }

    float r[4][4][4];                 // state [g'][z][s]
    int pm_count = 1, pz4 = 0, pb = 0, step = 0;

    for (int row = 0; row < NROW; ++row) {
        const int xs = (row == 0) ? 1 : 4;          // up bond (top edge -> 1)
        const int zs = (row == NROW - 1) ? 1 : 4;   // down bond (bottom -> 1)
        for (int c = 0; c < NCOL; ++c, ++step) {
            const int gin  = (c == 0) ? 1 : 4;
            const int gout = (c == NCOL - 1) ? 1 : 4;
            const int mbits = ((xs == 4) ? 2 * (5 - c) : 0) + ((zs == 4) ? 2 * c : 0);
            const int mcount = 1 << mbits;
            const int spin = (int)((sm >> step) & 1ull);
            const float* Ms = Tm + (size_t)(step * 2 + spin) * 256;  // uniform
            const bool act = (4 * t < mcount);

            float acc[4][4][4] = {};                // next state [gp][z][s]

            #pragma unroll
            for (int g = 0; g < 4; ++g) {
                if (g < gin) {                      // block-uniform
                    float* sb = buf[pb]; pb ^= 1;
                    // ---- stage slice g (b128, swizzled) ----
                    if (step == 0) {
                        if (t == 0) sb[0] = 1.0f;
                    } else if (4 * t + 3 < pm_count) {
                        if (pz4) {
                            #pragma unroll
                            for (int s = 0; s < 4; ++s)
                                *(float4*)&sb[SWZ(16 * t + 4 * s)] = make_float4(
                                    r[g][0][s], r[g][1][s], r[g][2][s], r[g][3][s]);
                        } else {
                            *(float4*)&sb[SWZ(4 * t)] = make_float4(
                                r[g][0][0], r[g][0][1], r[g][0][2], r[g][0][3]);
                        }
                    } else if (4 * t < pm_count) {  // pm_count==1 -> t==0 only
                        if (pz4)
                            *(float4*)&sb[0] = make_float4(
                                r[g][0][0], r[g][1][0], r[g][2][0], r[g][3][0]);
                        else
                            sb[0] = r[g][0][0];
                    }
                    __syncthreads();
                    // ---- read wv (b128, swizzled) ----
                    float wv[4][4];
                    if (act) {
                        if (mcount >= 4) {
                            #pragma unroll
                            for (int x = 0; x < 4; ++x) {
                                if (x < xs) {
                                    float4 rv = *(const float4*)&sb[SWZ(x * mcount + 4 * t)];
                                    wv[x][0] = rv.x; wv[x][1] = rv.y;
                                    wv[x][2] = rv.z; wv[x][3] = rv.w;
                                }
                            }
                        } else {                    // mcount==1 -> t==0 only
                            #pragma unroll
                            for (int x = 0; x < 4; ++x) {
                                if (x < xs) {
                                    wv[x][0] = sb[x];   // SWZ(x)==x for x<4
                                    wv[x][1] = wv[x][2] = wv[x][3] = 0.f;
                                }
                            }
                        }
                    }
                    // ---- FMA; M rows are uniform-address float4 loads ----
                    #pragma unroll
                    for (int gp = 0; gp < 4; ++gp) {
                        if (gp < gout) {
                            #pragma unroll
                            for (int z = 0; z < 4; ++z) {
                                if (z < zs) {
                                    const float4 mr = *(const float4*)&Ms[g * 64 + (gp * 4 + z) * 4];
                                    if (act) {
                                        #pragma unroll
                                        for (int x = 0; x < 4; ++x) {
                                            if (x < xs) {
                                                const float mv = (x == 0) ? mr.x
                                                               : (x == 1) ? mr.y
                                                               : (x == 2) ? mr.z : mr.w;
                                                #pragma unroll
                                                for (int s = 0; s < 4; ++s)
                                                    acc[gp][z][s] += mv * wv[x][s];
                                            }
                                        }
                                    }
                                }
                            }
                        }
                    }
                }
            }

            // ---- commit ----
            #pragma unroll
            for (int gp = 0; gp < 4; ++gp)
                #pragma unroll
                for (int z = 0; z < 4; ++z)
                    #pragma unroll
                    for (int s = 0; s < 4; ++s) r[gp][z][s] = acc[gp][z][s];
            pm_count = mcount;
            pz4 = (zs == 4) ? 1 : 0;
        }
    }
    // after (5,5): only gp=0, z=0, m=0 valid -> thread 0, s=0
    if (t == 0) out[b] = r[0][0][0];
}

extern "C" void kernel_launch(void* const* d_in, const int* in_sizes, int n_in,
                              void* d_out, int out_size, void* d_ws, size_t ws_size,
                              hipStream_t stream) {
    const int*   X  = (const int*)d_in[0];     // x: [1024, 36] int32
    const float* Tg = (const float*)d_in[1];   // T: [6,6,2,4,4,4,4] fp32
    float* out = (float*)d_out;                // reference output: float32
    float* Tm  = (float*)d_ws;                 // 73,728 B scratch
    (void)in_sizes; (void)n_in; (void)ws_size; (void)out_size;
    peps_reorder_kernel<<<dim3((NSITE * 2 * 256 + 255) / 256), dim3(256), 0, stream>>>(Tg, Tm);
    peps_amp_kernel<<<dim3(BATCH), dim3(256), 0, stream>>>(X, Tm, out);
}

// Round 7
// 399.069 us; speedup vs baseline: 1.4315x; 1.3706x over previous
//
#include <hip/hip_runtime.h>

#define NROW 6
#define NCOL 6
#define BATCH 1024
#define NSITE 36

// LDS address swizzle: XOR dword-addr bits [4:2] with bits [7:5]. The m=4t+s
// ownership makes b128 staging writes lane-stride 64B (8-way bank conflict
// without this); the swizzle spreads them over all 32 banks. Bits [1:0] are
// untouched so float4 contiguity and 16B alignment survive.
__device__ __forceinline__ int SWZ(int a) { return a ^ (((a >> 5) & 7) << 2); }

// Pre-transpose T[site][spin][u=x][r=gp][d=z][l=g] into
// Tm[((site*2+spin)*4+g)*64 + (gp*4+z)*4 + x]  (73,728 B in d_ws) so the main
// kernel's M rows are contiguous float4s at block-uniform addresses.
__global__ void peps_reorder_kernel(const float* __restrict__ T,
                                    float* __restrict__ Tm)
{
    int idx = blockIdx.x * 256 + threadIdx.x;
    if (idx >= NSITE * 2 * 256) return;
    int x  = idx & 3;
    int o  = (idx >> 2) & 15;         // o = gp*4 + z
    int g  = (idx >> 6) & 3;
    int sp = (idx >> 8) & 1;
    int st = idx >> 9;
    int gp = o >> 2, z = o & 3;
    Tm[idx] = T[st * 512 + sp * 256 + x * 64 + gp * 16 + z * 4 + g];
}

// One block = one sample; exact 6x6 PEPS (D=4) by row-major site absorption.
// State between steps lives in registers: thread t owns spectator indices
// m = 4t+s (s=0..3) for all 16 (g',z). Each step streams the state through a
// 16KB LDS slice per left-bond value g (parity double-buffered, 1 barrier per
// slice). All LDS traffic is b128 (see SWZ).
// OCCUPANCY IS THE BINDER (R3 vs R5/R6: occ 44%->439us, occ 24%->547us with
// less work): the ~126 barriers/block leave the VALU idle unless >=4 blocks/CU
// are resident to fill the bubbles. VGPR=76 fits the 128 cap of 4 waves/EU;
// LDS 32KB x 4 = 128KB <= 160KB. Hence __launch_bounds__(256, 4).
__global__ __launch_bounds__(256, 4)
void peps_amp_kernel(const int* __restrict__ X, const float* __restrict__ Tm,
                     float* __restrict__ out)
{
    __shared__ float buf[2][4096];    // 32 KB

    const int b = blockIdx.x;
    const int t = threadIdx.x;
    const int* xrow = X + b * NSITE;

    // PHYS=2: pack all 36 spins into one scalar 64-bit mask.
    unsigned long long sm = 0ull;
    const int4* xp = (const int4*)xrow;           // 36 ints = 9 aligned int4
    #pragma unroll
    for (int k = 0; k < 9; ++k) {
        int4 v = xp[k];
        sm |= ((unsigned long long)(v.x & 1)) << (4 * k + 0);
        sm |= ((unsigned long long)(v.y & 1)) << (4 * k + 1);
        sm |= ((unsigned long long)(v.z & 1)) << (4 * k + 2);
        sm |= ((unsigned long long)(v.w & 1)) << (4 * k + 3);
    }
    {   // force SGPR so the Tm addresses below are provably uniform
        unsigned lo = __builtin_amdgcn_readfirstlane((int)(sm & 0xffffffffull));
        unsigned hi = __builtin_amdgcn_readfirstlane((int)(sm >> 32));
        sm = ((unsigned long long)hi << 32) | lo;
    }

    float r[4][4][4];                 // state [g'][z][s]
    int pm_count = 1, pz4 = 0, pb = 0, step = 0;

    for (int row = 0; row < NROW; ++row) {
        const int xs = (row == 0) ? 1 : 4;          // up bond (top edge -> 1)
        const int zs = (row == NROW - 1) ? 1 : 4;   // down bond (bottom -> 1)
        for (int c = 0; c < NCOL; ++c, ++step) {
            const int gin  = (c == 0) ? 1 : 4;
            const int gout = (c == NCOL - 1) ? 1 : 4;
            const int mbits = ((xs == 4) ? 2 * (5 - c) : 0) + ((zs == 4) ? 2 * c : 0);
            const int mcount = 1 << mbits;
            const int spin = (int)((sm >> step) & 1ull);
            const float* Ms = Tm + (size_t)(step * 2 + spin) * 256;  // uniform
            const bool act = (4 * t < mcount);

            float acc[4][4][4] = {};                // next state [gp][z][s]

            #pragma unroll
            for (int g = 0; g < 4; ++g) {
                if (g < gin) {                      // block-uniform
                    float* sb = buf[pb]; pb ^= 1;
                    // ---- stage slice g (b128, swizzled) ----
                    if (step == 0) {
                        if (t == 0) sb[0] = 1.0f;
                    } else if (4 * t + 3 < pm_count) {
                        if (pz4) {
                            #pragma unroll
                            for (int s = 0; s < 4; ++s)
                                *(float4*)&sb[SWZ(16 * t + 4 * s)] = make_float4(
                                    r[g][0][s], r[g][1][s], r[g][2][s], r[g][3][s]);
                        } else {
                            *(float4*)&sb[SWZ(4 * t)] = make_float4(
                                r[g][0][0], r[g][0][1], r[g][0][2], r[g][0][3]);
                        }
                    } else if (4 * t < pm_count) {  // pm_count==1 -> t==0 only
                        if (pz4)
                            *(float4*)&sb[0] = make_float4(
                                r[g][0][0], r[g][1][0], r[g][2][0], r[g][3][0]);
                        else
                            sb[0] = r[g][0][0];
                    }
                    __syncthreads();
                    // ---- read wv (b128, swizzled) ----
                    float wv[4][4];
                    if (act) {
                        if (mcount >= 4) {
                            #pragma unroll
                            for (int x = 0; x < 4; ++x) {
                                if (x < xs) {
                                    float4 rv = *(const float4*)&sb[SWZ(x * mcount + 4 * t)];
                                    wv[x][0] = rv.x; wv[x][1] = rv.y;
                                    wv[x][2] = rv.z; wv[x][3] = rv.w;
                                }
                            }
                        } else {                    // mcount==1 -> t==0 only
                            #pragma unroll
                            for (int x = 0; x < 4; ++x) {
                                if (x < xs) {
                                    wv[x][0] = sb[x];   // SWZ(x)==x for x<4
                                    wv[x][1] = wv[x][2] = wv[x][3] = 0.f;
                                }
                            }
                        }
                    }
                    // ---- FMA; M rows are uniform-address float4 loads ----
                    #pragma unroll
                    for (int gp = 0; gp < 4; ++gp) {
                        if (gp < gout) {
                            #pragma unroll
                            for (int z = 0; z < 4; ++z) {
                                if (z < zs) {
                                    const float4 mr = *(const float4*)&Ms[g * 64 + (gp * 4 + z) * 4];
                                    if (act) {
                                        #pragma unroll
                                        for (int x = 0; x < 4; ++x) {
                                            if (x < xs) {
                                                const float mv = (x == 0) ? mr.x
                                                               : (x == 1) ? mr.y
                                                               : (x == 2) ? mr.z : mr.w;
                                                #pragma unroll
                                                for (int s = 0; s < 4; ++s)
                                                    acc[gp][z][s] += mv * wv[x][s];
                                            }
                                        }
                                    }
                                }
                            }
                        }
                    }
                }
            }

            // ---- commit ----
            #pragma unroll
            for (int gp = 0; gp < 4; ++gp)
                #pragma unroll
                for (int z = 0; z < 4; ++z)
                    #pragma unroll
                    for (int s = 0; s < 4; ++s) r[gp][z][s] = acc[gp][z][s];
            pm_count = mcount;
            pz4 = (zs == 4) ? 1 : 0;
        }
    }
    // after (5,5): only gp=0, z=0, m=0 valid -> thread 0, s=0
    if (t == 0) out[b] = r[0][0][0];
}

extern "C" void kernel_launch(void* const* d_in, const int* in_sizes, int n_in,
                              void* d_out, int out_size, void* d_ws, size_t ws_size,
                              hipStream_t stream) {
    const int*   X  = (const int*)d_in[0];     // x: [1024, 36] int32
    const float* Tg = (const float*)d_in[1];   // T: [6,6,2,4,4,4,4] fp32
    float* out = (float*)d_out;                // reference output: float32
    float* Tm  = (float*)d_ws;                 // 73,728 B scratch
    (void)in_sizes; (void)n_in; (void)ws_size; (void)out_size;
    peps_reorder_kernel<<<dim3((NSITE * 2 * 256 + 255) / 256), dim3(256), 0, stream>>>(Tg, Tm);
    peps_amp_kernel<<<dim3(BATCH), dim3(256), 0, stream>>>(X, Tm, out);
}